// Round 12
// baseline (413.634 us; speedup 1.0000x reference)
//
#include <hip/hip_runtime.h>
#include <hip/hip_bf16.h>

#define B_  8
#define D_  256
#define N_  8192
#define M_  8192
#define O1_ 512     // 2D
#define K1_ 768     // 3D
#define K2_ 512     // 2D

typedef unsigned short u16;
typedef __attribute__((ext_vector_type(8))) short bf8;   // 8 bf16 = 4 VGPRs
typedef __attribute__((ext_vector_type(4))) float f4;

static __device__ __forceinline__ float bf2f(u16 u) {
    unsigned v = ((unsigned)u) << 16;
    return __uint_as_float(v);
}
static __device__ __forceinline__ u16 f2bf(float f) {
    __hip_bfloat16 h = __float2bfloat16(f);
    return *reinterpret_cast<u16*>(&h);
}
// async global->LDS, 16B per lane; LDS dest = wave-uniform base + lane*16
static __device__ __forceinline__ void gl_lds16(const u16* g, u16* l) {
    __builtin_amdgcn_global_load_lds((const __attribute__((address_space(1))) void*)g,
                                     (__attribute__((address_space(3))) void*)l, 16, 0, 0);
}
// byte-offset swizzle within a 64B LDS row (bits 4,5 from row bits 1,2) — 0 conflicts (R8-verified)
static __device__ __forceinline__ int swz64(int r) {
    return (((r >> 1) & 1) << 4) | (((r >> 2) & 1) << 5);
}

// ---------------- transpose f32 [B][D][8192] -> bf16 [B][8192][D], all 4 tensors in one launch ----------------
__global__ __launch_bounds__(256) void k_transpose_all(const float* __restrict__ s0, const float* __restrict__ s1,
                                                       const float* __restrict__ s2, const float* __restrict__ s3,
                                                       u16* __restrict__ dA, u16* __restrict__ dB) {
    __shared__ float t[32][33];
    const int z = blockIdx.z;
    const int sel = z >> 3, b = z & 7;        // sel: 0=ldesc0 1=ldesc1 2=le0 3=le1
    const float* src = (sel == 0) ? s0 : (sel == 1) ? s1 : (sel == 2) ? s2 : s3;
    u16* dst = ((sel < 2) ? dA : dB) + (size_t)(sel & 1) * B_ * N_ * D_;
    const int c0 = blockIdx.x * 32, r0 = blockIdx.y * 32;
    const int tx = threadIdx.x, ty = threadIdx.y;     // block (32,8)
    const float* s = src + (size_t)b * D_ * N_;
    u16* d = dst + (size_t)b * N_ * D_;
#pragma unroll
    for (int i = 0; i < 4; ++i) {
        int r = r0 + ty + i * 8;
        t[ty + i * 8][tx] = s[(size_t)r * N_ + (c0 + tx)];
    }
    __syncthreads();
#pragma unroll
    for (int i = 0; i < 4; ++i) {
        int c = c0 + ty + i * 8;
        d[(size_t)c * D_ + (r0 + tx)] = f2bf(t[tx][ty + i * 8]);
    }
}

// ---------------- weights f32 -> bf16 ----------------
__global__ __launch_bounds__(256) void k_convert_w(const float* __restrict__ W1, const float* __restrict__ W2,
                                                   u16* __restrict__ W1b, u16* __restrict__ W2b) {
    int i = blockIdx.x * 256 + threadIdx.x;
    const int n1 = O1_ * K1_;
    const int n2 = D_ * K2_;
    if (i < n1) W1b[i] = f2bf(W1[i]);
    int j = i - n1;
    if (j >= 0 && j < n2) W2b[j] = f2bf(W2[j]);
}

// ---------------- GEMM1: 256x256 tile, 8 waves, BK=64 (2 ks-planes), 8-phase dbuf, counted vmcnt ----------------
// both sides in one launch: z = side*8 + b ; fused BN-stats epilogue (LA reused as scratch)
#define NT1 12    // K1/64
__global__ __launch_bounds__(512, 2) void k_gemm1(const u16* __restrict__ W1b,
                                                  const u16* __restrict__ Tld2,
                                                  const u16* __restrict__ Tle2,
                                                  const int* __restrict__ idx0,
                                                  const int* __restrict__ idx1,
                                                  u16* __restrict__ hbuf2,
                                                  float* __restrict__ stats) {
    __shared__ u16 LA[2][2][256][32];   // [buf][ks][row o][32 u16 = 64B] : 64 KB
    __shared__ u16 LB[2][2][256][32];   // [buf][ks][row m][...]          : 64 KB
    const int z  = blockIdx.z;
    const int side = z >> 3, b = z & 7;
    const u16* Tld = Tld2 + (size_t)side * B_ * N_ * D_;
    const u16* Tle = Tle2 + (size_t)side * B_ * N_ * D_;
    const int* idx = side ? idx1 : idx0;
    u16* hbuf = hbuf2 + (size_t)side * B_ * M_ * O1_;
    const int o0 = blockIdx.y * 256;
    const int m0 = blockIdx.x * 256;
    const int tid = threadIdx.x;
    const int w = tid >> 6, l = tid & 63;
    const int wr = w >> 2;      // o half: 128 rows
    const int wc = w & 3;       // m quarter: 64 rows

    const int srow   = tid >> 2;          // 0..127
    const int schunk = (tid & 3) * 16;    // byte offset in 64B row

    int na[2], nb[2], mm[2];
    const u16* aS[2];
    int bcolu[2];
#pragma unroll
    for (int j = 0; j < 2; ++j) {
        int r = j * 128 + srow;
        int m = m0 + r;
        mm[j] = m;
        na[j] = idx[b * M_ + m];
        nb[j] = idx[b * M_ + (m ^ 1)];
        int swu = (schunk ^ swz64(r)) >> 1;          // pre-swizzled source chunk (u16)
        aS[j]   = W1b + (size_t)(o0 + r) * K1_ + swu;
        bcolu[j] = swu;
    }

    int aOff[8], bOff[4];
#pragma unroll
    for (int i = 0; i < 8; ++i) {
        int r = wr * 128 + i * 16 + (l & 15);
        aOff[i] = r * 32 + ((((l >> 4) * 16) ^ swz64(r)) >> 1);
    }
#pragma unroll
    for (int j = 0; j < 4; ++j) {
        int r = wc * 64 + j * 16 + (l & 15);
        bOff[j] = r * 32 + ((((l >> 4) * 16) ^ swz64(r)) >> 1);
    }

#define STAGE_A1(kt, ks, buf)                                                        \
    {                                                                                \
        _Pragma("unroll")                                                            \
        for (int j = 0; j < 2; ++j)                                                  \
            gl_lds16(aS[j] + (kt) * 64 + (ks) * 32, &LA[buf][ks][j * 128][0] + tid * 8); \
    }
#define STAGE_B1(kt, ks, buf)                                                        \
    {                                                                                \
        const int seg = (kt) >> 2;                                                   \
        const int cb  = ((kt) & 3) * 64 + (ks) * 32;                                 \
        _Pragma("unroll")                                                            \
        for (int j = 0; j < 2; ++j) {                                                \
            const u16* s;                                                            \
            if (seg == 0)      s = Tld + (size_t)(b * N_ + na[j]) * D_ + cb + bcolu[j]; \
            else if (seg == 1) s = Tld + (size_t)(b * N_ + nb[j]) * D_ + cb + bcolu[j]; \
            else               s = Tle + (size_t)(b * M_ + mm[j]) * D_ + cb + bcolu[j]; \
            gl_lds16(s, &LB[buf][ks][j * 128][0] + tid * 8);                         \
        }                                                                            \
    }

    f4 acc[8][4];
#pragma unroll
    for (int i = 0; i < 8; ++i)
#pragma unroll
        for (int j = 0; j < 4; ++j) acc[i][j] = {0.f, 0.f, 0.f, 0.f};

    STAGE_A1(0, 0, 0); STAGE_B1(0, 0, 0);
    STAGE_A1(0, 1, 0); STAGE_B1(0, 1, 0);
    STAGE_A1(1, 0, 1); STAGE_B1(1, 0, 1);
    asm volatile("s_waitcnt vmcnt(8)" ::: "memory");
    __builtin_amdgcn_s_barrier();
    __builtin_amdgcn_sched_barrier(0);

    for (int t = 0; t < NT1; ++t) {
        const int bufp = t & 1, nbuf = bufp ^ 1;
        const u16* baseA0 = &LA[bufp][0][0][0];
        const u16* baseA1 = &LA[bufp][1][0][0];
        const u16* baseB0 = &LB[bufp][0][0][0];
        const u16* baseB1 = &LB[bufp][1][0][0];
        bf8 aF[4], bF[4];

        // ---- phase 0: (qi=0, ks=0) ----
#pragma unroll
        for (int j = 0; j < 4; ++j) bF[j] = *reinterpret_cast<const bf8*>(baseB0 + bOff[j]);
#pragma unroll
        for (int ii = 0; ii < 4; ++ii) aF[ii] = *reinterpret_cast<const bf8*>(baseA0 + aOff[ii]);
        if (t + 1 < NT1) STAGE_A1(t + 1, 1, nbuf);
        __builtin_amdgcn_s_barrier();
        asm volatile("s_waitcnt lgkmcnt(0)" ::: "memory");
        __builtin_amdgcn_sched_barrier(0);
        __builtin_amdgcn_s_setprio(1);
#pragma unroll
        for (int ii = 0; ii < 4; ++ii)
#pragma unroll
            for (int j = 0; j < 4; ++j)
                acc[ii][j] = __builtin_amdgcn_mfma_f32_16x16x32_bf16(aF[ii], bF[j], acc[ii][j], 0, 0, 0);
        __builtin_amdgcn_s_setprio(0);
        __builtin_amdgcn_s_barrier();
        __builtin_amdgcn_sched_barrier(0);

        // ---- phase 1: (qi=1, ks=0)  [bF reused] ----
#pragma unroll
        for (int ii = 0; ii < 4; ++ii) aF[ii] = *reinterpret_cast<const bf8*>(baseA0 + aOff[4 + ii]);
        if (t + 1 < NT1) STAGE_B1(t + 1, 1, nbuf);
        __builtin_amdgcn_s_barrier();
        asm volatile("s_waitcnt lgkmcnt(0)" ::: "memory");
        __builtin_amdgcn_sched_barrier(0);
        __builtin_amdgcn_s_setprio(1);
#pragma unroll
        for (int ii = 0; ii < 4; ++ii)
#pragma unroll
            for (int j = 0; j < 4; ++j)
                acc[4 + ii][j] = __builtin_amdgcn_mfma_f32_16x16x32_bf16(aF[ii], bF[j], acc[4 + ii][j], 0, 0, 0);
        __builtin_amdgcn_s_setprio(0);
        if (t < NT1 - 2) asm volatile("s_waitcnt vmcnt(8)" ::: "memory");
        else             asm volatile("s_waitcnt vmcnt(0)" ::: "memory");
        __builtin_amdgcn_s_barrier();
        __builtin_amdgcn_sched_barrier(0);

        // ---- phase 2: (qi=0, ks=1) ----
#pragma unroll
        for (int j = 0; j < 4; ++j) bF[j] = *reinterpret_cast<const bf8*>(baseB1 + bOff[j]);
#pragma unroll
        for (int ii = 0; ii < 4; ++ii) aF[ii] = *reinterpret_cast<const bf8*>(baseA1 + aOff[ii]);
        if (t + 2 < NT1) STAGE_A1(t + 2, 0, bufp);
        __builtin_amdgcn_s_barrier();
        asm volatile("s_waitcnt lgkmcnt(0)" ::: "memory");
        __builtin_amdgcn_sched_barrier(0);
        __builtin_amdgcn_s_setprio(1);
#pragma unroll
        for (int ii = 0; ii < 4; ++ii)
#pragma unroll
            for (int j = 0; j < 4; ++j)
                acc[ii][j] = __builtin_amdgcn_mfma_f32_16x16x32_bf16(aF[ii], bF[j], acc[ii][j], 0, 0, 0);
        __builtin_amdgcn_s_setprio(0);
        __builtin_amdgcn_s_barrier();
        __builtin_amdgcn_sched_barrier(0);

        // ---- phase 3: (qi=1, ks=1)  [bF reused] ----
#pragma unroll
        for (int ii = 0; ii < 4; ++ii) aF[ii] = *reinterpret_cast<const bf8*>(baseA1 + aOff[4 + ii]);
        if (t + 2 < NT1) STAGE_B1(t + 2, 0, bufp);
        __builtin_amdgcn_s_barrier();
        asm volatile("s_waitcnt lgkmcnt(0)" ::: "memory");
        __builtin_amdgcn_sched_barrier(0);
        __builtin_amdgcn_s_setprio(1);
#pragma unroll
        for (int ii = 0; ii < 4; ++ii)
#pragma unroll
            for (int j = 0; j < 4; ++j)
                acc[4 + ii][j] = __builtin_amdgcn_mfma_f32_16x16x32_bf16(aF[ii], bF[j], acc[4 + ii][j], 0, 0, 0);
        __builtin_amdgcn_s_setprio(0);
        if (t < NT1 - 2) asm volatile("s_waitcnt vmcnt(8)" ::: "memory");
        else             asm volatile("s_waitcnt vmcnt(0)" ::: "memory");
        __builtin_amdgcn_s_barrier();
        __builtin_amdgcn_sched_barrier(0);
    }
#undef STAGE_A1
#undef STAGE_B1

    // ---- fused BN stats: per-channel sum/sumsq over this block's 256 m (LA dead -> scratch) ----
    float* redS = (float*)&LA[0][0][0][0];          // [256 ch][4 wc] = 4 KB
    float* redQ = (float*)&LA[0][0][0][0] + 1024;   // next 4 KB
#pragma unroll
    for (int i = 0; i < 8; ++i) {
#pragma unroll
        for (int r = 0; r < 4; ++r) {
            float s = acc[i][0][r] + acc[i][1][r] + acc[i][2][r] + acc[i][3][r];
            float q = acc[i][0][r] * acc[i][0][r] + acc[i][1][r] * acc[i][1][r]
                    + acc[i][2][r] * acc[i][2][r] + acc[i][3][r] * acc[i][3][r];
#pragma unroll
            for (int mk = 1; mk < 16; mk <<= 1) {
                s += __shfl_xor(s, mk, 16);
                q += __shfl_xor(q, mk, 16);
            }
            if ((l & 15) == 0) {
                int ch = wr * 128 + i * 16 + (l >> 4) * 4 + r;
                redS[ch * 4 + wc] = s;
                redQ[ch * 4 + wc] = q;
            }
        }
    }
    __syncthreads();
    if (tid < 256) {
        float s = redS[tid * 4] + redS[tid * 4 + 1] + redS[tid * 4 + 2] + redS[tid * 4 + 3];
        float q = redQ[tid * 4] + redQ[tid * 4 + 1] + redQ[tid * 4 + 2] + redQ[tid * 4 + 3];
        atomicAdd(&stats[side * 1024 + o0 + tid], s);
        atomicAdd(&stats[side * 1024 + 512 + o0 + tid], q);
    }

    // epilogue: store bf16 h' to hbuf[b][m][o] (o fast)
#pragma unroll
    for (int j = 0; j < 4; ++j) {
        int m = m0 + wc * 64 + j * 16 + (l & 15);
        size_t rowbase = (size_t)(b * M_ + m) * O1_;
#pragma unroll
        for (int i = 0; i < 8; ++i) {
            int orow = o0 + wr * 128 + i * 16 + (l >> 4) * 4;
            ushort4 pk;
            pk.x = f2bf(acc[i][j].x);
            pk.y = f2bf(acc[i][j].y);
            pk.z = f2bf(acc[i][j].z);
            pk.w = f2bf(acc[i][j].w);
            *reinterpret_cast<ushort4*>(&hbuf[rowbase + orow]) = pk;
        }
    }
}

__global__ void k_finalize_ac(const float* __restrict__ stats, const float* __restrict__ g1,
                              const float* __restrict__ bt1, float* __restrict__ ac) {
    int i = blockIdx.x * 256 + threadIdx.x;   // 0..1023
    if (i >= 1024) return;
    int side = i >> 9, o = i & 511;
    const float* st = stats + side * 1024;
    const float inv = 1.0f / ((float)B_ * (float)M_);
    float mean = st[o] * inv;
    float var  = st[O1_ + o] * inv - mean * mean;
    var = fmaxf(var, 0.0f);
    float a = g1[o] * rsqrtf(var + 1e-5f);
    ac[side * 1024 + o] = a;
    ac[side * 1024 + O1_ + o] = bt1[o] - mean * a;   // b1 cancels: shift = bt1 - a*mean(h')
}

// ---------------- CSR build (both sides): count -> scan -> fill ----------------
__global__ void k_count_int(const int* __restrict__ idx0, const int* __restrict__ idx1, int* __restrict__ cnt2) {
    int i = blockIdx.x * 256 + threadIdx.x;       // 0 .. 2*B*M
    if (i < 2 * B_ * M_) {
        int side = i >> 16, j = i & 65535;
        const int* idx = side ? idx1 : idx0;
        atomicAdd(&cnt2[side * B_ * N_ + (j >> 13) * N_ + idx[j]], 1);
    }
}

__global__ __launch_bounds__(1024) void k_scan(const int* __restrict__ cnt2, int* __restrict__ offs2,
                                               int* __restrict__ fill2) {
    __shared__ int wsum[1024];
    const int base = blockIdx.x * N_;    // blockIdx.x = side*8+b
    const int t = threadIdx.x;
    int v[8]; int s = 0;
#pragma unroll
    for (int k = 0; k < 8; ++k) { v[k] = cnt2[base + t * 8 + k]; s += v[k]; }
    wsum[t] = s;
    __syncthreads();
    for (int off = 1; off < 1024; off <<= 1) {
        int add = (t >= off) ? wsum[t - off] : 0;
        __syncthreads();
        wsum[t] += add;
        __syncthreads();
    }
    int run = (t > 0) ? wsum[t - 1] : 0;
#pragma unroll
    for (int k = 0; k < 8; ++k) {
        offs2[base + t * 8 + k] = run;
        fill2[base + t * 8 + k] = run;
        run += v[k];
    }
}

__global__ void k_fill(const int* __restrict__ idx0, const int* __restrict__ idx1,
                       int* __restrict__ fill2, int* __restrict__ mlist2) {
    int i = blockIdx.x * 256 + threadIdx.x;
    if (i < 2 * B_ * M_) {
        int side = i >> 16, j = i & 65535;
        const int* idx = side ? idx1 : idx0;
        int b = j >> 13, m = j & (M_ - 1);
        int pos = atomicAdd(&fill2[side * B_ * N_ + b * N_ + idx[j]], 1);
        mlist2[(size_t)side * B_ * M_ + b * M_ + pos] = m;
    }
}

// ---------------- GEMM2: up[b][m][d] = W2 @ relu(a*h'+c) + b2 ----------------
// Full-D tile (256) per block so each hbuf row is staged+transformed ONCE. 512 threads (2x4 waves).
__global__ __launch_bounds__(512) void k_gemm2(const u16* __restrict__ W2b,
                                               const u16* __restrict__ hbuf2,
                                               const float* __restrict__ ac,
                                               const float* __restrict__ b2,
                                               u16* __restrict__ up2) {
    __shared__ u16 At[256 * 32];      // [256 d][32 u16] swizzled, 16 KB
    __shared__ u16 Bt[128 * 32];      // [128 m][32 u16] swizzled, 8 KB
    __shared__ float acs[1024];       // [0,512) scale a, [512,1024) shift c
    __shared__ float bcs[256];        // b2
    const int z = blockIdx.z;
    const int side = z >> 3, b = z & 7;
    const u16* hbuf = hbuf2 + (size_t)side * B_ * M_ * O1_;
    u16* up = up2 + (size_t)side * B_ * M_ * D_;
    const float* acp = ac + side * 1024;
    const int m0 = blockIdx.x * 128;
    const int tid = threadIdx.x;
    const int w = tid >> 6, l = tid & 63;
    const int wr = w >> 2;    // d half: 128 rows -> 8 frags
    const int wc = w & 3;     // m quarter: 32 -> 2 frags

    acs[tid]       = acp[tid];
    acs[tid + 512] = acp[tid + 512];
    if (tid < 256) bcs[tid] = b2[tid];

    const int srow   = tid >> 2;          // 0..127
    const int schunk = (tid & 3) * 16;    // byte chunk in 64B row
    const int lcu    = (tid & 3) * 8;     // u16 chunk offset (unswizzled, for source & coeffs)

    // A: W2b rows srow, srow+128 ; pre-swizzled global source (LDS dest linear)
    const u16* aS[2];
#pragma unroll
    for (int j = 0; j < 2; ++j) {
        int r = j * 128 + srow;
        aS[j] = W2b + (size_t)r * K2_ + ((schunk ^ swz64(r)) >> 1);
    }
    // B: hbuf row m0+srow, reg-staged with BN transform, swizzled ds_write
    const u16* pB = hbuf + (size_t)(b * M_ + m0 + srow) * O1_ + lcu;
    u16* bDst = &Bt[srow * 32 + ((schunk ^ swz64(srow)) >> 1)];

    int aOff[8], bOff[2];
#pragma unroll
    for (int i = 0; i < 8; ++i) {
        int r = wr * 128 + i * 16 + (l & 15);
        aOff[i] = r * 32 + ((((l >> 4) * 16) ^ swz64(r)) >> 1);
    }
#pragma unroll
    for (int j = 0; j < 2; ++j) {
        int r = wc * 32 + j * 16 + (l & 15);
        bOff[j] = r * 32 + ((((l >> 4) * 16) ^ swz64(r)) >> 1);
    }

    f4 acc[8][2];
#pragma unroll
    for (int i = 0; i < 8; ++i)
#pragma unroll
        for (int j = 0; j < 2; ++j) acc[i][j] = {0.f, 0.f, 0.f, 0.f};

    __syncthreads();   // acs/bcs visible

    for (int kk = 0; kk < 16; ++kk) {
        const int o = kk * 32 + lcu;
        f4 A0 = *reinterpret_cast<const f4*>(&acs[o]);
        f4 A1 = *reinterpret_cast<const f4*>(&acs[o + 4]);
        f4 C0 = *reinterpret_cast<const f4*>(&acs[512 + o]);
        f4 C1 = *reinterpret_cast<const f4*>(&acs[512 + o + 4]);
#pragma unroll
        for (int j = 0; j < 2; ++j)
            gl_lds16(aS[j] + kk * 32, At + j * 128 * 32 + tid * 8);
        {
            const ushort4* ps = reinterpret_cast<const ushort4*>(pB + kk * 32);
            ushort4 v0 = ps[0], v1 = ps[1];
            union { ushort4 u4[2]; bf8 v8; } pk;
            pk.u4[0].x = f2bf(fmaxf(bf2f(v0.x) * A0.x + C0.x, 0.0f));
            pk.u4[0].y = f2bf(fmaxf(bf2f(v0.y) * A0.y + C0.y, 0.0f));
            pk.u4[0].z = f2bf(fmaxf(bf2f(v0.z) * A0.z + C0.z, 0.0f));
            pk.u4[0].w = f2bf(fmaxf(bf2f(v0.w) * A0.w + C0.w, 0.0f));
            pk.u4[1].x = f2bf(fmaxf(bf2f(v1.x) * A1.x + C1.x, 0.0f));
            pk.u4[1].y = f2bf(fmaxf(bf2f(v1.y) * A1.y + C1.y, 0.0f));
            pk.u4[1].z = f2bf(fmaxf(bf2f(v1.z) * A1.z + C1.z, 0.0f));
            pk.u4[1].w = f2bf(fmaxf(bf2f(v1.w) * A1.w + C1.w, 0.0f));
            *reinterpret_cast<bf8*>(bDst) = pk.v8;
        }
        __syncthreads();
        bf8 aF[8], bF[2];
#pragma unroll
        for (int i = 0; i < 8; ++i) aF[i] = *reinterpret_cast<const bf8*>(&At[aOff[i]]);
#pragma unroll
        for (int j = 0; j < 2; ++j) bF[j] = *reinterpret_cast<const bf8*>(&Bt[bOff[j]]);
#pragma unroll
        for (int i = 0; i < 8; ++i)
#pragma unroll
            for (int j = 0; j < 2; ++j)
                acc[i][j] = __builtin_amdgcn_mfma_f32_16x16x32_bf16(aF[i], bF[j], acc[i][j], 0, 0, 0);
        __syncthreads();
    }

    // epilogue: +b2, plain bf16 stores to up[b][m][d]
#pragma unroll
    for (int j = 0; j < 2; ++j) {
        int m = m0 + wc * 32 + j * 16 + (l & 15);
        size_t rowbase = (size_t)(b * M_ + m) * D_;
#pragma unroll
        for (int i = 0; i < 8; ++i) {
            int d = wr * 128 + i * 16 + (l >> 4) * 4;
            ushort4 pk;
            pk.x = f2bf(acc[i][j].x + bcs[d + 0]);
            pk.y = f2bf(acc[i][j].y + bcs[d + 1]);
            pk.z = f2bf(acc[i][j].z + bcs[d + 2]);
            pk.w = f2bf(acc[i][j].w + bcs[d + 3]);
            *reinterpret_cast<ushort4*>(&up[rowbase + d]) = pk;
        }
    }
}

// ---------------- out[b][d][n] = ldesc + mean_{m in list(n)} up[b][m][d], both sides ----------------
__global__ __launch_bounds__(256) void k_reduce_finalize(const float* __restrict__ ldesc0,
                                                         const float* __restrict__ ldesc1,
                                                         const u16* __restrict__ up2,
                                                         const int* __restrict__ cnt2,
                                                         const int* __restrict__ offs2,
                                                         const int* __restrict__ mlist2,
                                                         float* __restrict__ out) {
    __shared__ float lds[32][257];
    const int z = blockIdx.z;
    const int side = z >> 3, b = z & 7;
    const float* ldesc = side ? ldesc1 : ldesc0;
    const u16* up = up2 + (size_t)side * B_ * M_ * D_;
    const int* cnt  = cnt2  + side * B_ * N_;
    const int* offs = offs2 + side * B_ * N_;
    const int* mlist = mlist2 + (size_t)side * B_ * M_;
    float* outp = out + (size_t)side * B_ * D_ * N_;
    const int n0 = blockIdx.x * 32;
    const int tx = threadIdx.x, ty = threadIdx.y;   // (32,8)
#pragma unroll
    for (int i = 0; i < 4; ++i) {
        int nl = ty + i * 8;
        int n  = n0 + nl;
        int c   = cnt[b * N_ + n];
        int off = offs[b * N_ + n];
        float inv = 1.0f / (float)max(c, 1);
        float acc[8] = {0.f, 0.f, 0.f, 0.f, 0.f, 0.f, 0.f, 0.f};
        for (int e = 0; e < c; ++e) {
            int m = mlist[(size_t)b * M_ + off + e];
            const ushort4* row = reinterpret_cast<const ushort4*>(up + (size_t)(b * M_ + m) * D_ + tx * 8);
            ushort4 aa = row[0], bb = row[1];
            acc[0] += bf2f(aa.x); acc[1] += bf2f(aa.y); acc[2] += bf2f(aa.z); acc[3] += bf2f(aa.w);
            acc[4] += bf2f(bb.x); acc[5] += bf2f(bb.y); acc[6] += bf2f(bb.z); acc[7] += bf2f(bb.w);
        }
#pragma unroll
        for (int k = 0; k < 8; ++k) lds[nl][tx * 8 + k] = acc[k] * inv;
    }
    __syncthreads();
#pragma unroll
    for (int i = 0; i < 32; ++i) {
        int d = ty + i * 8;
        size_t o2 = (size_t)(b * D_ + d) * N_ + n0 + tx;
        outp[o2] = ldesc[o2] + lds[tx][d];
    }
}

__global__ void k_marker(float* out, float v) { out[0] = v; }

extern "C" void kernel_launch(void* const* d_in, const int* in_sizes, int n_in,
                              void* d_out, int out_size, void* d_ws, size_t ws_size,
                              hipStream_t stream) {
    const float* ldesc0 = (const float*)d_in[0];
    const float* ldesc1 = (const float*)d_in[1];
    const float* le0    = (const float*)d_in[2];
    const float* le1    = (const float*)d_in[3];
    const int*   idx0   = (const int*)d_in[4];
    const int*   idx1   = (const int*)d_in[5];
    const float* W1     = (const float*)d_in[6];
    const float* g1     = (const float*)d_in[8];
    const float* bt1    = (const float*)d_in[9];
    const float* W2     = (const float*)d_in[10];
    const float* b2     = (const float*)d_in[11];
    float* out = (float*)d_out;

    char* ws = (char*)d_ws;
    const size_t SIDE_BND = (size_t)B_ * N_ * D_ * 2;   // 33,554,432 B (bf16 [B][N][D])
    const size_t oTld2  = 0;                            // 2 sides: 67,108,864 (aliased by up2 later)
    const size_t oTle2  = 2 * SIDE_BND;                 // 2 sides: 67,108,864 (aliased by CSR later)
    const size_t oH2    = 4 * SIDE_BND;                 // 2 sides bf16 [B][M][O1]: 134,217,728
    const size_t oW1b   = oH2 + (size_t)2 * B_ * M_ * O1_ * 2;   // 268,435,456
    const size_t oW2b   = oW1b + 786432;
    const size_t oStats = oW2b + 262144;
    const size_t oAC    = oStats + 8192;
    const size_t NEED   = oAC + 8192;
    if (ws_size < NEED) {
        k_marker<<<1, 1, 0, stream>>>(out, 1000.0f + (float)(ws_size >> 20));
        return;
    }
    u16*   Tld2  = (u16*)(ws + oTld2);
    u16*   up2   = (u16*)(ws + oTld2);                  // alias (Tld dead after gemm1)
    u16*   Tle2  = (u16*)(ws + oTle2);
    int*   cnt2  = (int*)(ws + oTle2);                  // CSR aliases Tle2 (dead after gemm1)
    int*   offs2 = (int*)(ws + oTle2 + 524288);
    int*   fill2 = (int*)(ws + oTle2 + 1048576);
    int*   mlist2= (int*)(ws + oTle2 + 1572864);
    u16*   hbuf2 = (u16*)(ws + oH2);
    u16*   W1b   = (u16*)(ws + oW1b);
    u16*   W2b   = (u16*)(ws + oW2b);
    float* stats = (float*)(ws + oStats);
    float* ac    = (float*)(ws + oAC);

    k_convert_w<<<2048, 256, 0, stream>>>(W1, W2, W1b, W2b);

    const dim3 tb(32, 8);
    // 1) all 4 transposes in one launch
    k_transpose_all<<<dim3(N_ / 32, D_ / 32, 32), tb, 0, stream>>>(ldesc0, ldesc1, le0, le1, Tld2, Tle2);
    // 2) gemm1 both sides (fused BN stats); stats must be zeroed first
    hipMemsetAsync(stats, 0, 8192, stream);
    k_gemm1<<<dim3(M_ / 256, O1_ / 256, 16), 512, 0, stream>>>(W1b, Tld2, Tle2, idx0, idx1, hbuf2, stats);
    k_finalize_ac<<<4, 256, 0, stream>>>(stats, g1, bt1, ac);
    // 3) CSR both sides (Tle2 region dead now)
    hipMemsetAsync(cnt2, 0, (size_t)2 * B_ * N_ * 4, stream);
    k_count_int<<<2 * B_ * M_ / 256, 256, 0, stream>>>(idx0, idx1, cnt2);
    k_scan<<<16, 1024, 0, stream>>>(cnt2, offs2, fill2);
    k_fill<<<2 * B_ * M_ / 256, 256, 0, stream>>>(idx0, idx1, fill2, mlist2);
    // 4) gemm2 both sides (Tld2 region dead now): full-D tile, then gather-mean + residual
    k_gemm2<<<dim3(M_ / 128, 1, 16), 512, 0, stream>>>(W2b, hbuf2, ac, b2, up2);
    k_reduce_finalize<<<dim3(N_ / 32, 1, 16), tb, 0, stream>>>(ldesc0, ldesc1, up2, cnt2, offs2, mlist2, out);
}